// Round 1
// baseline (260.253 us; speedup 1.0000x reference)
//
#include <hip/hip_runtime.h>
#include <hip/hip_bf16.h>
#include <math.h>

// Problem constants
#define NN 8192
#define KK 128
#define DD 128

typedef short bf16x8 __attribute__((ext_vector_type(8)));
typedef float f32x4 __attribute__((ext_vector_type(4)));

// ---------------- P1: log_softmax of weigh (1 block, 128 threads) ----------------
__global__ void prep_w(const float* __restrict__ weigh, float* __restrict__ wlog) {
    __shared__ float sm[KK];
    int t = threadIdx.x;
    float v = weigh[t];
    sm[t] = v; __syncthreads();
    for (int off = 64; off > 0; off >>= 1) { if (t < off) sm[t] = fmaxf(sm[t], sm[t + off]); __syncthreads(); }
    float m = sm[0]; __syncthreads();
    sm[t] = expf(v - m); __syncthreads();
    for (int off = 64; off > 0; off >>= 1) { if (t < off) sm[t] += sm[t + off]; __syncthreads(); }
    float lse = m + logf(sm[0]);
    wlog[t] = v - lse;
}

// ---------------- P2: per-component M_k (bf16), b_k, c_k = logdet + w ----------------
__global__ void prep_k(const float* __restrict__ means, const float* __restrict__ logvar,
                       const float* __restrict__ tri, const float* __restrict__ wlog,
                       __hip_bfloat16* __restrict__ Mb, float* __restrict__ bvec,
                       float* __restrict__ cvec) {
    int k = blockIdx.x;
    int j = threadIdx.x;   // 128 threads
    __shared__ float svar[DD], smean[DD], sred[DD];
    float lv  = logvar[k * DD + j];
    float var = expf(tanhf(lv));
    svar[j]  = var;
    smean[j] = means[k * DD + j];
    sred[j]  = logf(var + 1e-8f);
    __syncthreads();
    for (int off = 64; off > 0; off >>= 1) { if (j < off) sred[j] += sred[j + off]; __syncthreads(); }
    float logdet = sred[0];

    const float* trik = tri + (size_t)k * DD * DD;
    __hip_bfloat16* Mk = Mb + (size_t)k * DD * DD;
    // M[i][j] = (j<i) ? tri[i][j]*var[j] : (j==i ? var[j] : 0)   (coalesced in j)
    for (int i = 0; i < DD; i++) {
        float v = 0.f;
        if (j < i)       v = trik[i * DD + j] * svar[j];
        else if (j == i) v = svar[j];
        Mk[i * DD + j] = __float2bfloat16(v);
    }
    // b_i = M_i . mean  (thread i owns row i)
    {
        int i = j;
        float acc = svar[i] * smean[i];
        for (int jj = 0; jj < i; jj++) acc += trik[i * DD + jj] * svar[jj] * smean[jj];
        bvec[k * DD + i] = acc;
    }
    if (j == 0) cvec[k] = logdet + wlog[k];
}

// ---------------- P3: X -> bf16 ----------------
__global__ void prep_x(const float* __restrict__ X, __hip_bfloat16* __restrict__ Xb) {
    int i = blockIdx.x * blockDim.x + threadIdx.x;
    if (i < NN * DD) Xb[i] = __float2bfloat16(X[i]);
}

// ---------------- Main: per (n-tile=128, k) block: Z = X@M^T, q, logits ----------------
__global__ __launch_bounds__(256) void gemm_q(const __hip_bfloat16* __restrict__ Xb,
                                              const __hip_bfloat16* __restrict__ Mb,
                                              const float* __restrict__ bvec,
                                              const float* __restrict__ cvec,
                                              float* __restrict__ logitsT) {
    __shared__ uint4 sA[2048];   // 128 rows x 128 bf16 (row-major, contiguous k-dim)
    __shared__ uint4 sB[2048];   // M[i][j]: 128 rows(i=col of Z) x 128 (j=k-dim)
    __shared__ float sb[DD];
    int tid = threadIdx.x;
    int n0  = blockIdx.x * 128;
    int k   = blockIdx.y;

    const uint4* gA = (const uint4*)Xb + (size_t)n0 * 16;          // 16 uint4 per row
    const uint4* gB = (const uint4*)(Mb + (size_t)k * DD * DD);
#pragma unroll
    for (int i = 0; i < 8; i++) {
        int idx = i * 256 + tid;
        sA[idx] = gA[idx];
        sB[idx] = gB[idx];
    }
    if (tid < DD) sb[tid] = bvec[k * DD + tid];
    float ck = cvec[k];
    __syncthreads();

    int lane = tid & 63, w = tid >> 6;
    int quad = lane >> 4, l15 = lane & 15;

    f32x4 acc[2][8];
#pragma unroll
    for (int rt = 0; rt < 2; rt++)
#pragma unroll
        for (int ct = 0; ct < 8; ct++) acc[rt][ct] = (f32x4){0.f, 0.f, 0.f, 0.f};

    const char* A8 = (const char*)sA;
    const char* B8 = (const char*)sB;
#pragma unroll
    for (int s = 0; s < 4; s++) {
        bf16x8 af[2];
#pragma unroll
        for (int rt = 0; rt < 2; rt++) {
            int row = w * 32 + rt * 16 + l15;
            af[rt] = *(const bf16x8*)(A8 + row * 256 + s * 64 + quad * 16);
        }
#pragma unroll
        for (int ct = 0; ct < 8; ct++) {
            int col = ct * 16 + l15;
            bf16x8 bfr = *(const bf16x8*)(B8 + col * 256 + s * 64 + quad * 16);
#pragma unroll
            for (int rt = 0; rt < 2; rt++)
                acc[rt][ct] = __builtin_amdgcn_mfma_f32_16x16x32_bf16(af[rt], bfr, acc[rt][ct], 0, 0, 0);
        }
    }

    // Epilogue: q[row] = sum_col (Z - b[col])^2 ; logitsT[k][n] = -q/2 + c[k]
#pragma unroll
    for (int rt = 0; rt < 2; rt++) {
        float rs[4] = {0.f, 0.f, 0.f, 0.f};
#pragma unroll
        for (int ct = 0; ct < 8; ct++) {
            float bb = sb[ct * 16 + l15];
#pragma unroll
            for (int r = 0; r < 4; r++) {
                float z = acc[rt][ct][r] - bb;
                rs[r] += z * z;
            }
        }
#pragma unroll
        for (int r = 0; r < 4; r++) {
#pragma unroll
            for (int off = 1; off < 16; off <<= 1)
                rs[r] += __shfl_xor(rs[r], off, 64);
        }
        if (l15 == 0) {
            int nbase = n0 + w * 32 + rt * 16 + quad * 4;
            float* dst = logitsT + (size_t)k * NN + nbase;
#pragma unroll
            for (int r = 0; r < 4; r++) dst[r] = -0.5f * rs[r] + ck;
        }
    }
}

// ---------------- Finalize: per-n logsumexp over K, mean, output scalar ----------------
__global__ void finalize(const float* __restrict__ logitsT, float* __restrict__ out) {
    __shared__ float sred[256];
    int t = threadIdx.x;
    int n = blockIdx.x * 256 + t;
    float m = -INFINITY, s = 0.f;
    for (int k = 0; k < KK; k++) {
        float v = logitsT[(size_t)k * NN + n];
        if (v > m) { s = s * expf(m - v) + 1.f; m = v; }
        else       { s += expf(v - m); }
    }
    float lse = m + logf(s);
    const float logC = -64.f * 1.8378770664093453f;   // -d/2 * log(2*pi), d=128
    float contrib = (-logC - lse) * (1.f / (float)NN);
    sred[t] = contrib; __syncthreads();
    for (int off = 128; off > 0; off >>= 1) { if (t < off) sred[t] += sred[t + off]; __syncthreads(); }
    if (t == 0) atomicAdd(out, sred[0]);
}

extern "C" void kernel_launch(void* const* d_in, const int* in_sizes, int n_in,
                              void* d_out, int out_size, void* d_ws, size_t ws_size,
                              hipStream_t stream) {
    const float* X      = (const float*)d_in[0];
    const float* means  = (const float*)d_in[1];
    const float* logvar = (const float*)d_in[2];
    const float* tri    = (const float*)d_in[3];
    const float* weigh  = (const float*)d_in[4];
    float* out = (float*)d_out;

    char* ws = (char*)d_ws;
    __hip_bfloat16* Mb      = (__hip_bfloat16*)(ws);                  // 4 MiB
    __hip_bfloat16* Xb      = (__hip_bfloat16*)(ws + 4194304);        // 2 MiB
    float*          logitsT = (float*)(ws + 6291456);                 // 4 MiB (K x N)
    float*          bvec    = (float*)(ws + 10485760);                // 64 KiB
    float*          wlog    = (float*)(ws + 10551296);                // 512 B
    float*          cvec    = (float*)(ws + 10551808);                // 512 B

    hipMemsetAsync(d_out, 0, sizeof(float), stream);

    prep_w<<<1, 128, 0, stream>>>(weigh, wlog);
    prep_k<<<KK, 128, 0, stream>>>(means, logvar, tri, wlog, Mb, bvec, cvec);
    prep_x<<<(NN * DD + 255) / 256, 256, 0, stream>>>(X, Xb);

    dim3 grid(NN / 128, KK);
    gemm_q<<<grid, 256, 0, stream>>>(Xb, Mb, bvec, cvec, logitsT);

    finalize<<<NN / 256, 256, 0, stream>>>(logitsT, out);
}

// Round 2
// 184.222 us; speedup vs baseline: 1.4127x; 1.4127x over previous
//
#include <hip/hip_runtime.h>
#include <hip/hip_bf16.h>
#include <math.h>

#define NN 8192
#define KK 128
#define DD 128

typedef short bf16x8 __attribute__((ext_vector_type(8)));
typedef float f32x4 __attribute__((ext_vector_type(4)));

static __device__ __forceinline__ short f2bf(float f) {
    __hip_bfloat16 h = __float2bfloat16(f);
    return __builtin_bit_cast(short, h);
}

// ---------------- prep_k: M_k (bf16), b_k = M_k*mean_k, c_k = logdet + logsoftmax(w)_k
// grid (KK, 4), 256 threads. Block (k, slice) builds rows [slice*32, slice*32+32).
__global__ __launch_bounds__(256) void prep_k(const float* __restrict__ means,
                                              const float* __restrict__ logvar,
                                              const float* __restrict__ tri,
                                              const float* __restrict__ weigh,
                                              __hip_bfloat16* __restrict__ Mb,
                                              float* __restrict__ bvec,
                                              float* __restrict__ cvec) {
    int k = blockIdx.x, slice = blockIdx.y;
    int t = threadIdx.x;
    __shared__ float svar[DD], smean[DD], red[DD];
    if (t < DD) {
        float var = expf(tanhf(logvar[k * DD + t]));
        svar[t]  = var;
        smean[t] = means[k * DD + t];
        red[t]   = logf(var + 1e-8f);
    }
    __syncthreads();

    int w = t >> 6, lane = t & 63;
    const float* trik = tri + (size_t)k * DD * DD;
    __hip_bfloat16* Mk = Mb + (size_t)k * DD * DD;
#pragma unroll
    for (int rr = 0; rr < 8; rr++) {
        int i = slice * 32 + w * 8 + rr;
        int j0 = lane, j1 = lane + 64;
        float m0 = (j0 < i) ? trik[i * DD + j0] * svar[j0] : ((j0 == i) ? svar[j0] : 0.f);
        float m1 = (j1 < i) ? trik[i * DD + j1] * svar[j1] : ((j1 == i) ? svar[j1] : 0.f);
        Mk[i * DD + j0] = __float2bfloat16(m0);
        Mk[i * DD + j1] = __float2bfloat16(m1);
        float b = m0 * smean[j0] + m1 * smean[j1];
#pragma unroll
        for (int off = 32; off; off >>= 1) b += __shfl_xor(b, off, 64);
        if (lane == 0) bvec[k * DD + i] = b;
    }

    __syncthreads();
    if (slice == 0 && t < 64) {
        float ld = red[t] + red[t + 64];
#pragma unroll
        for (int off = 32; off; off >>= 1) ld += __shfl_xor(ld, off, 64);
        float w0 = weigh[t], w1 = weigh[t + 64];
        float mx = fmaxf(w0, w1);
#pragma unroll
        for (int off = 32; off; off >>= 1) mx = fmaxf(mx, __shfl_xor(mx, off, 64));
        float e = expf(w0 - mx) + expf(w1 - mx);
#pragma unroll
        for (int off = 32; off; off >>= 1) e += __shfl_xor(e, off, 64);
        if (t == 0) cvec[k] = ld + weigh[k] - (mx + logf(e));
    }
}

// ---------------- gemm_q: barrier-free streaming GEMM + q epilogue.
// grid (NN/256, KK/8), 256 threads. Wave w owns rows n0+w*64..+63 (rt=4 tiles of 16).
// A (X tile) lives in registers (converted f32->bf16 once); B fragments stream
// directly global->VGPR (16B contiguous in M_k row-major layout). No LDS.
__global__ __launch_bounds__(256, 1) void gemm_q(const float* __restrict__ X,
                                                 const __hip_bfloat16* __restrict__ Mb,
                                                 const float* __restrict__ bvec,
                                                 const float* __restrict__ cvec,
                                                 float* __restrict__ logitsT) {
    int tid  = threadIdx.x;
    int w    = tid >> 6, lane = tid & 63;
    int quad = lane >> 4, l15 = lane & 15;
    int n0 = blockIdx.x * 256;
    int k0 = blockIdx.y * 8;

    // A fragments: af[rt][s] covers row n0+w*64+rt*16+l15, k-elems s*32+quad*8..+8
    bf16x8 af[4][4];
#pragma unroll
    for (int rt = 0; rt < 4; rt++) {
        const float* xr = X + (size_t)(n0 + w * 64 + rt * 16 + l15) * DD;
#pragma unroll
        for (int s = 0; s < 4; s++) {
            const float* p = xr + s * 32 + quad * 8;
            float4 x0 = *(const float4*)(p);
            float4 x1 = *(const float4*)(p + 4);
            bf16x8 a;
            a[0] = f2bf(x0.x); a[1] = f2bf(x0.y); a[2] = f2bf(x0.z); a[3] = f2bf(x0.w);
            a[4] = f2bf(x1.x); a[5] = f2bf(x1.y); a[6] = f2bf(x1.z); a[7] = f2bf(x1.w);
            af[rt][s] = a;
        }
    }

    const char* Bbase = (const char*)Mb;
#pragma unroll 1
    for (int kk = 0; kk < 8; kk++) {
        int k = k0 + kk;
        const char* Bk = Bbase + (size_t)k * (DD * DD * 2);
        float ck = cvec[k];
        float bb[8];
#pragma unroll
        for (int ct = 0; ct < 8; ct++) bb[ct] = bvec[k * DD + ct * 16 + l15];

        f32x4 acc[4][8];
#pragma unroll
        for (int rt = 0; rt < 4; rt++)
#pragma unroll
            for (int ct = 0; ct < 8; ct++) acc[rt][ct] = (f32x4){0.f, 0.f, 0.f, 0.f};

#pragma unroll
        for (int s = 0; s < 4; s++) {
            bf16x8 bfr[8];
#pragma unroll
            for (int ct = 0; ct < 8; ct++)
                bfr[ct] = *(const bf16x8*)(Bk + (ct * 16 + l15) * 256 + s * 64 + quad * 16);
#pragma unroll
            for (int ct = 0; ct < 8; ct++)
#pragma unroll
                for (int rt = 0; rt < 4; rt++)
                    acc[rt][ct] = __builtin_amdgcn_mfma_f32_16x16x32_bf16(af[rt][s], bfr[ct], acc[rt][ct], 0, 0, 0);
        }

        // q[row] = sum_col (Z-b)^2 ; logitsT[k][n] = -q/2 + c_k
#pragma unroll
        for (int rt = 0; rt < 4; rt++) {
            float rs[4] = {0.f, 0.f, 0.f, 0.f};
#pragma unroll
            for (int ct = 0; ct < 8; ct++) {
                float bbv = bb[ct];
#pragma unroll
                for (int r = 0; r < 4; r++) {
                    float z = acc[rt][ct][r] - bbv;
                    rs[r] = fmaf(z, z, rs[r]);
                }
            }
#pragma unroll
            for (int r = 0; r < 4; r++) {
#pragma unroll
                for (int off = 1; off < 16; off <<= 1)
                    rs[r] += __shfl_xor(rs[r], off, 64);
            }
            if (l15 == 0) {
                float4 o;
                o.x = fmaf(rs[0], -0.5f, ck);
                o.y = fmaf(rs[1], -0.5f, ck);
                o.z = fmaf(rs[2], -0.5f, ck);
                o.w = fmaf(rs[3], -0.5f, ck);
                *(float4*)(logitsT + (size_t)k * NN + n0 + w * 64 + rt * 16 + quad * 4) = o;
            }
        }
    }
}

// ---------------- finalize: logsumexp over K per n, mean. grid NN/64 blocks x 256.
__global__ __launch_bounds__(256) void finalize(const float* __restrict__ logitsT,
                                                float* __restrict__ out) {
    __shared__ float sm[4][64], ss[4][64], sred[64];
    int t = threadIdx.x;
    int tn = t & 63, tk = t >> 6;
    int n = blockIdx.x * 64 + tn;
    float m = -INFINITY, s = 0.f;
#pragma unroll 4
    for (int kc = 0; kc < 32; kc++) {
        int k = tk * 32 + kc;
        float v = logitsT[(size_t)k * NN + n];
        float nm = fmaxf(m, v);
        s = s * expf(m - nm) + expf(v - nm);
        m = nm;
    }
    sm[tk][tn] = m; ss[tk][tn] = s;
    __syncthreads();
    if (tk == 0) {
        float M = fmaxf(fmaxf(sm[0][tn], sm[1][tn]), fmaxf(sm[2][tn], sm[3][tn]));
        float S = ss[0][tn] * expf(sm[0][tn] - M) + ss[1][tn] * expf(sm[1][tn] - M)
                + ss[2][tn] * expf(sm[2][tn] - M) + ss[3][tn] * expf(sm[3][tn] - M);
        float lse = M + logf(S);
        const float logC = -64.f * 1.8378770664093453f;
        sred[tn] = (-logC - lse) * (1.f / (float)NN);
    }
    __syncthreads();
    if (t < 64) {
        float v = sred[t];
#pragma unroll
        for (int off = 32; off; off >>= 1) v += __shfl_xor(v, off, 64);
        if (t == 0) atomicAdd(out, v);
    }
}

extern "C" void kernel_launch(void* const* d_in, const int* in_sizes, int n_in,
                              void* d_out, int out_size, void* d_ws, size_t ws_size,
                              hipStream_t stream) {
    const float* X      = (const float*)d_in[0];
    const float* means  = (const float*)d_in[1];
    const float* logvar = (const float*)d_in[2];
    const float* tri    = (const float*)d_in[3];
    const float* weigh  = (const float*)d_in[4];
    float* out = (float*)d_out;

    char* ws = (char*)d_ws;
    __hip_bfloat16* Mb      = (__hip_bfloat16*)(ws);              // 4 MiB
    float*          logitsT = (float*)(ws + 4194304);             // 4 MiB (K x N)
    float*          bvec    = (float*)(ws + 8388608);             // 64 KiB
    float*          cvec    = (float*)(ws + 8454144);             // 512 B

    hipMemsetAsync(d_out, 0, sizeof(float), stream);

    prep_k<<<dim3(KK, 4), 256, 0, stream>>>(means, logvar, tri, weigh, Mb, bvec, cvec);
    gemm_q<<<dim3(NN / 256, KK / 8), 256, 0, stream>>>(X, Mb, bvec, cvec, logitsT);
    finalize<<<NN / 64, 256, 0, stream>>>(logitsT, out);
}